// Round 2
// baseline (394.049 us; speedup 1.0000x reference)
//
#include <hip/hip_runtime.h>
#include <hip/hip_bf16.h>

// Embedding gather: out[i, :] = table[ids[i], :]
// ids: delivered as int32 by harness ("integer -> const int*"), [819200]
// table: float32 [1000000, 64], out: float32 [819200, 64]
// Row = 256 B = 16 x float4. 16 lanes per row, one float4 per lane:
// each row-read is one coalesced 256 B segment; wave writes 1 KiB coalesced.

__global__ __launch_bounds__(256) void OnlineEmbedding_64484638982170_kernel(
    const int* __restrict__ ids,
    const float4* __restrict__ table,   // [VOCAB * 16] float4
    float4* __restrict__ out,           // [N * 16] float4
    int total_vec)                      // N * 16
{
    int tid = blockIdx.x * blockDim.x + threadIdx.x;
    if (tid >= total_vec) return;
    int row = tid >> 4;          // which output row
    int col = tid & 15;          // which float4 within the row
    long long id = (long long)ids[row];  // 16 lanes read same address (broadcast)
    out[tid] = table[id * 16 + col];
}

extern "C" void kernel_launch(void* const* d_in, const int* in_sizes, int n_in,
                              void* d_out, int out_size, void* d_ws, size_t ws_size,
                              hipStream_t stream) {
    const int* ids      = (const int*)d_in[0];     // [BATCH*HIST] int32 per harness
    const float4* table = (const float4*)d_in[1];  // [VOCAB, 64] f32 as float4
    float4* out         = (float4*)d_out;

    const int n_rows = in_sizes[0];        // 819200
    const int total_vec = n_rows * 16;     // one float4 per thread

    const int block = 256;
    const int grid = (total_vec + block - 1) / block;
    OnlineEmbedding_64484638982170_kernel<<<grid, block, 0, stream>>>(
        ids, table, out, total_vec);
}